// Round 1
// baseline (17103.615 us; speedup 1.0000x reference)
//
#include <hip/hip_runtime.h>
#include <stdint.h>

// EchoStateNetwork MI355X:
//  - 64 independent sequences (b,ch); h_{t+1} = 0.9*tanh(W_in u_t(b) + W_res^T h_t) + 0.1*h_t
//  - Phase A: inp[t][b][k] = u . W_in, stashed into out[b][0][t][k] (consumed then
//    overwritten by the recurrence at exactly step t, same block, sync between).
//  - Phase B: persistent kernel, 256 blocks = 8 seq-groups x 32 col-blocks.
//    W_res column slice in VGPRs (32 float4/thread). h exchanged through d_out with
//    relaxed agent-scope atomics (IF$-coherent, XCD-placement independent) +
//    per-group monotonic flag barrier. Deadlock-safe: all 256 blocks co-resident.

#define H_  1024
#define T_  1024
#define B_  16
#define CH_ 4
#define D_  64
#define F_  256   // CH*D

// ---------------- Phase A: inp GEMM (fp32, LDS tiled 64x64, K=256 in 4 chunks) ---
__global__ __launch_bounds__(256) void inp_gemm(const float* __restrict__ x,
                                                const float* __restrict__ W_in,
                                                float* __restrict__ out)
{
    __shared__ float U[64 * 68];    // [t 64][f 68]  (pad 68 -> conflict-free a reads)
    __shared__ float Wt[64 * 66];   // [f 64][k 66]  (transposed W_in tile)
    const int k0 = blockIdx.x * 64;
    const int t0 = blockIdx.y * 64;
    const int b  = blockIdx.z;
    const int tid = threadIdx.x;
    const int ty = tid >> 4, tx = tid & 15;     // 4x4 outputs per thread

    float4 acc[4];
    acc[0] = float4{0.f,0.f,0.f,0.f}; acc[1] = acc[0]; acc[2] = acc[0]; acc[3] = acc[0];

    for (int fc = 0; fc < 4; ++fc) {            // f-chunk == channel fc
        {   // stage U: thread (t_l, fs): 16 floats of x[b][fc][t0+t_l][fs*16..]
            const int t_l = tid >> 2, fs = tid & 3;
            const float* src = x + ((size_t)(b * CH_ + fc) * T_ + (t0 + t_l)) * D_ + fs * 16;
            float* dst = &U[t_l * 68 + fs * 16];
            #pragma unroll
            for (int q = 0; q < 4; ++q)
                ((float4*)dst)[q] = ((const float4*)src)[q];
        }
        {   // stage Wt (transpose): thread (k_l, fs): W_in[k0+k_l][fc*64 + fs*16..]
            const int k_l = tid >> 2, fs = tid & 3;
            const float* src = W_in + (size_t)(k0 + k_l) * F_ + fc * 64 + fs * 16;
            float4 v[4];
            #pragma unroll
            for (int q = 0; q < 4; ++q) v[q] = ((const float4*)src)[q];
            #pragma unroll
            for (int q = 0; q < 4; ++q) {
                Wt[(fs*16 + q*4 + 0) * 66 + k_l] = v[q].x;
                Wt[(fs*16 + q*4 + 1) * 66 + k_l] = v[q].y;
                Wt[(fs*16 + q*4 + 2) * 66 + k_l] = v[q].z;
                Wt[(fs*16 + q*4 + 3) * 66 + k_l] = v[q].w;
            }
        }
        __syncthreads();
        #pragma unroll 4
        for (int f4 = 0; f4 < 16; ++f4) {
            float4 a[4], bk[4];
            #pragma unroll
            for (int r = 0; r < 4; ++r)  a[r]  = *(const float4*)&U[(ty*4 + r) * 68 + f4*4];
            #pragma unroll
            for (int kk = 0; kk < 4; ++kk) bk[kk] = *(const float4*)&Wt[(f4*4 + kk) * 66 + tx*4];
            #pragma unroll
            for (int r = 0; r < 4; ++r) {
                const float4 av = a[r];
                acc[r].x = fmaf(av.x, bk[0].x, acc[r].x); acc[r].y = fmaf(av.x, bk[0].y, acc[r].y);
                acc[r].z = fmaf(av.x, bk[0].z, acc[r].z); acc[r].w = fmaf(av.x, bk[0].w, acc[r].w);
                acc[r].x = fmaf(av.y, bk[1].x, acc[r].x); acc[r].y = fmaf(av.y, bk[1].y, acc[r].y);
                acc[r].z = fmaf(av.y, bk[1].z, acc[r].z); acc[r].w = fmaf(av.y, bk[1].w, acc[r].w);
                acc[r].x = fmaf(av.z, bk[2].x, acc[r].x); acc[r].y = fmaf(av.z, bk[2].y, acc[r].y);
                acc[r].z = fmaf(av.z, bk[2].z, acc[r].z); acc[r].w = fmaf(av.z, bk[2].w, acc[r].w);
                acc[r].x = fmaf(av.w, bk[3].x, acc[r].x); acc[r].y = fmaf(av.w, bk[3].y, acc[r].y);
                acc[r].z = fmaf(av.w, bk[3].z, acc[r].z); acc[r].w = fmaf(av.w, bk[3].w, acc[r].w);
            }
        }
        __syncthreads();
    }
    // stash inp tile into out[b][0][t0+ty*4+r][k0+tx*4..]
    #pragma unroll
    for (int r = 0; r < 4; ++r) {
        float* dst = out + ((size_t)(b * CH_) * T_ + (t0 + ty*4 + r)) * H_ + k0 + tx*4;
        *(float4*)dst = acc[r];
    }
}

// ---------------- Phase B: persistent recurrence --------------------------------
// grid 256 = group(8, low 3 bits) x colblock(32). 256 threads.
// thread: kr = tid>>3 (h-range kr*32..+32), cg = tid&7 (4 cols: C0+cg*4..)
// W regs: w4[kk] = W_res[kr*32+kk][C0+cg*4 .. +4]
// LDS smem[9216]: h skewed [s][1152] (36 floats per 32-chunk) overlaid later by
// partials [s][kr 32][33].
__global__ __launch_bounds__(256, 1) void esn_recur(const float* __restrict__ Wres,
                                                    float* __restrict__ out,
                                                    unsigned int* __restrict__ flags)
{
    __shared__ float smem[9216];
    const int bx  = blockIdx.x;
    const int grp = bx & 7;                 // seq-group: bc in [grp*8, grp*8+8)
    const int j   = bx >> 3;                // col-block
    const int C0  = j * 32;
    const int tid = threadIdx.x;
    const int kr  = tid >> 3;               // 0..31
    const int cg  = tid & 7;                // 0..7
    // epilogue / staging mapping
    const int es   = tid >> 5;              // seq-local 0..7
    const int ecol = tid & 31;              // col within block slice
    const int bc   = grp * 8 + es;
    const size_t seqBase = (size_t)bc * (T_ * H_);
    const size_t inpBase = (size_t)(bc & ~3) * (T_ * H_);   // out[b][0] stash region

    // W_res slice -> registers (one-time, L2-shared across the 8 groups)
    float4 w4[32];
    #pragma unroll
    for (int kk = 0; kk < 32; ++kk)
        w4[kk] = *(const float4*)&Wres[(size_t)(kr * 32 + kk) * H_ + C0 + cg * 4];

    for (int idx = tid; idx < 9216; idx += 256) smem[idx] = 0.f;   // h_0 = 0
    __syncthreads();

    unsigned int* flag = flags + grp * 64;  // 256B-spaced counters

    for (int t = 0; t < T_; ++t) {
        if (t > 0) {
            if (tid == 0) {
                const unsigned int target = 32u * (unsigned)t;
                int guard = 0;
                while (__hip_atomic_load(flag, __ATOMIC_RELAXED, __HIP_MEMORY_SCOPE_AGENT) < target) {
                    __builtin_amdgcn_s_sleep(2);
                    if (++guard > (1 << 20)) break;   // deadman: wrong-answer over hang
                }
            }
            __syncthreads();
            __builtin_amdgcn_fence(__ATOMIC_ACQUIRE, "agent");
        }

        // prefetch inp value for this thread's epilogue output (slot overwritten
        // by this block later this step -- read-before-write w/ sync between)
        const float inp_v = __hip_atomic_load(out + inpBase + (size_t)t * H_ + C0 + ecol,
                                              __ATOMIC_RELAXED, __HIP_MEMORY_SCOPE_AGENT);

        if (t > 0) {  // stage h_t = out[bc][t-1][:] for the 8 seqs (skewed into LDS)
            const size_t g0 = (size_t)(grp * 8 + es) * (T_ * H_) + (size_t)(t - 1) * H_ + ecol * 32;
            const unsigned long long* gp = (const unsigned long long*)(out + g0);
            float* dst = &smem[es * 1152 + ecol * 36];
            #pragma unroll
            for (int q = 0; q < 16; ++q) {
                unsigned long long v = __hip_atomic_load((unsigned long long*)(gp + q),
                                                         __ATOMIC_RELAXED, __HIP_MEMORY_SCOPE_AGENT);
                *(unsigned long long*)(dst + q * 2) = v;
            }
        }
        __syncthreads();

        // matvec: acc[s][c] = sum_{h in kr-range} h_lds[s][h] * W[h][C0+cg*4+c]
        float4 acc4[8];
        #pragma unroll
        for (int s = 0; s < 8; ++s) acc4[s] = float4{0.f,0.f,0.f,0.f};
        const int hbase = kr * 36;
        #pragma unroll
        for (int c8 = 0; c8 < 8; ++c8) {
            const float4 wv0 = w4[c8*4+0], wv1 = w4[c8*4+1], wv2 = w4[c8*4+2], wv3 = w4[c8*4+3];
            #pragma unroll
            for (int s = 0; s < 8; ++s) {
                const float4 hv = *(const float4*)&smem[s * 1152 + hbase + c8 * 4];
                float4 a = acc4[s];
                a.x = fmaf(hv.x, wv0.x, a.x); a.y = fmaf(hv.x, wv0.y, a.y);
                a.z = fmaf(hv.x, wv0.z, a.z); a.w = fmaf(hv.x, wv0.w, a.w);
                a.x = fmaf(hv.y, wv1.x, a.x); a.y = fmaf(hv.y, wv1.y, a.y);
                a.z = fmaf(hv.y, wv1.z, a.z); a.w = fmaf(hv.y, wv1.w, a.w);
                a.x = fmaf(hv.z, wv2.x, a.x); a.y = fmaf(hv.z, wv2.y, a.y);
                a.z = fmaf(hv.z, wv2.z, a.z); a.w = fmaf(hv.z, wv2.w, a.w);
                a.x = fmaf(hv.w, wv3.x, a.x); a.y = fmaf(hv.w, wv3.y, a.y);
                a.z = fmaf(hv.w, wv3.z, a.z); a.w = fmaf(hv.w, wv3.w, a.w);
                acc4[s] = a;
            }
        }

        // old state for leak term (read BEFORE partials overlay h region)
        const float h_old = smem[es * 1152 + j * 36 + ecol];
        __syncthreads();

        // partials [s][kr][33] (+33 stride => 2-way max, free)
        #pragma unroll
        for (int s = 0; s < 8; ++s) {
            float* pp = &smem[s * 1056 + kr * 33 + cg * 4];
            pp[0] = acc4[s].x; pp[1] = acc4[s].y; pp[2] = acc4[s].z; pp[3] = acc4[s].w;
        }
        __syncthreads();

        // reduce over kr + epilogue
        float sum = 0.f;
        #pragma unroll
        for (int k2 = 0; k2 < 32; ++k2) sum += smem[es * 1056 + k2 * 33 + ecol];
        const float pre = inp_v + sum;
        const float nv  = 0.9f * tanhf(pre) + 0.1f * h_old;
        __hip_atomic_store(out + seqBase + (size_t)t * H_ + C0 + ecol, nv,
                           __ATOMIC_RELAXED, __HIP_MEMORY_SCOPE_AGENT);

        __syncthreads();   // per-wave vmcnt(0) drain before barrier => stores at IF$
        if (tid == 0)
            __hip_atomic_fetch_add(flag, 1u, __ATOMIC_RELEASE, __HIP_MEMORY_SCOPE_AGENT);
    }
}

extern "C" void kernel_launch(void* const* d_in, const int* in_sizes, int n_in,
                              void* d_out, int out_size, void* d_ws, size_t ws_size,
                              hipStream_t stream) {
    const float* x    = (const float*)d_in[0];
    const float* W_in = (const float*)d_in[1];
    const float* Wres = (const float*)d_in[2];
    float* out = (float*)d_out;
    unsigned int* flags = (unsigned int*)d_ws;

    hipMemsetAsync(flags, 0, 4096, stream);
    inp_gemm<<<dim3(16, 16, 16), 256, 0, stream>>>(x, W_in, out);
    esn_recur<<<dim3(256), 256, 0, stream>>>(Wres, out, flags);
}